// Round 6
// baseline (743.976 us; speedup 1.0000x reference)
//
#include <hip/hip_runtime.h>
#include <hip/hip_bf16.h>

#define N_IN_F 384
#define N_HID  128
#define N_OUT  64

typedef unsigned short ushort_t;
typedef __attribute__((ext_vector_type(8))) short short8v;   // 8 bf16 (4 VGPRs)
typedef __attribute__((ext_vector_type(4))) float floatx4;   // MFMA C/D

union U8 { uint4 v; unsigned short u[8]; };

__device__ __forceinline__ float bfu2f(unsigned short s){
    union { unsigned i; float f; } c; c.i = ((unsigned)s) << 16; return c.f;
}
__device__ __forceinline__ unsigned short f2bfu(float f){
    __hip_bfloat16 h = __float2bfloat16(f);
    union { __hip_bfloat16 h; unsigned short u; } c; c.h = h; return c.u;
}

// fm == 1: tensor is bf16; fm == 0: tensor is float32
__device__ __forceinline__ float loadS(const void* p, size_t i, int fm){
    return fm ? bfu2f(((const unsigned short*)p)[i]) : ((const float*)p)[i];
}

// ---------------- dtype probes ----------------
__global__ void k_detect_all(const int* __restrict__ ei, const unsigned* __restrict__ xw,
                             int* __restrict__ modep){
    int lane = threadIdx.x & 63;
    int zi = 0;
    if (lane < 32) zi = ei[2*lane + 1];
    int cnt = 0;
    #pragma unroll
    for (int q = 0; q < 8; q++){
        unsigned w = xw[lane*8 + q];
        unsigned elo = (w >> 7) & 0xff;
        cnt += (elo >= 118 && elo <= 134) ? 1 : 0;
    }
    #pragma unroll
    for (int m = 32; m; m >>= 1){ zi |= __shfl_xor(zi, m, 64); cnt += __shfl_xor(cnt, m, 64); }
    if (lane == 0 && blockIdx.x == 0){
        modep[0] = (zi == 0) ? 1 : 0;
        modep[1] = (cnt >= 256) ? 1 : 0;
    }
}

__device__ __forceinline__ int edge_src(const int* ei, int e, int i, int mode){
    return mode ? ei[2*(size_t)i] : ei[i];
}
__device__ __forceinline__ int edge_dst(const int* ei, int e, int i, int mode){
    return mode ? ei[2*(size_t)e + 2*(size_t)i] : ei[(size_t)e + i];
}

// ---------------- CSR build ----------------
__global__ void k_hist(const int* __restrict__ ei, int e, int n, const int* __restrict__ modep,
                       int* __restrict__ deg, unsigned* __restrict__ rel){
    int i = blockIdx.x * 256 + threadIdx.x;
    if (i >= e) return;
    int mode = modep[0];
    int d = edge_dst(ei, e, i, mode);
    if ((unsigned)d >= (unsigned)n) return;
    rel[i] = (unsigned)atomicAdd(&deg[d], 1);
}

__global__ __launch_bounds__(1024) void k_blksum(
    const int* __restrict__ deg, int n, int* __restrict__ part)
{
    __shared__ int s[1024];
    int i = blockIdx.x * 1024 + threadIdx.x;
    s[threadIdx.x] = (i < n) ? deg[i] : 0;
    __syncthreads();
    for (int off = 512; off; off >>= 1){
        if (threadIdx.x < off) s[threadIdx.x] += s[threadIdx.x + off];
        __syncthreads();
    }
    if (threadIdx.x == 0) part[blockIdx.x] = s[0];
}

__global__ __launch_bounds__(128) void k_scanpart(
    int* __restrict__ part, int nb, int* __restrict__ rowoff, int n)
{
    __shared__ int s[128];
    int t = threadIdx.x;
    if (nb <= 128){
        int v = (t < nb) ? part[t] : 0;
        s[t] = v; __syncthreads();
        #pragma unroll
        for (int off = 1; off < 128; off <<= 1){
            int tmp = (t >= off) ? s[t - off] : 0;
            __syncthreads();
            s[t] += tmp;
            __syncthreads();
        }
        if (t < nb) part[t] = s[t] - v;
        if (t == 127) rowoff[n] = s[127];
    } else if (t == 0){
        int run = 0;
        for (int b = 0; b < nb; b++){ int tt = part[b]; part[b] = run; run += tt; }
        rowoff[n] = run;
    }
}

__global__ __launch_bounds__(1024) void k_scanblk(
    int* __restrict__ deg, const int* __restrict__ part, int n, int* __restrict__ rowoff)
{
    __shared__ int s[1024];
    int t = threadIdx.x;
    int i = blockIdx.x * 1024 + t;
    int v = (i < n) ? deg[i] : 0;
    s[t] = v; __syncthreads();
    for (int off = 1; off < 1024; off <<= 1){
        int tmp = (t >= off) ? s[t - off] : 0;
        __syncthreads();
        s[t] += tmp;
        __syncthreads();
    }
    if (i < n){
        int excl = s[t] - v + part[blockIdx.x];
        rowoff[i] = excl;
        deg[i]    = excl;   // deg becomes the scatter cursor (fallback path)
    }
}

// ---- fallback scatter (random 8B writes) for degenerate shapes (B > 1024) ----
__global__ void k_scatter(const int* __restrict__ ei, const void* __restrict__ ea,
                          int e, int n, const int* __restrict__ modep,
                          int* __restrict__ cursor, int2* __restrict__ colw)
{
    int i = blockIdx.x * 256 + threadIdx.x;
    if (i >= e) return;
    int mode = modep[0], fm = modep[1];
    int d = edge_dst(ei, e, i, mode);
    if ((unsigned)d >= (unsigned)n) return;
    int s = edge_src(ei, e, i, mode);
    if ((unsigned)s >= (unsigned)n) s = 0;
    int pos = atomicAdd(&cursor[d], 1);
    if ((unsigned)pos >= (unsigned)e) return;
    int2 pk; pk.x = s; pk.y = __float_as_int(loadS(ea, i, fm));
    colw[pos] = pk;
}

// ---- phase C: block-local counting sort by pos-bucket, sequential dump ----
#define SC_CHUNK 2048
#define SC_BSHIFT 13
#define SC_MAXB 1024
__global__ __launch_bounds__(256) void k_scoarse(
    const int* __restrict__ ei, const void* __restrict__ ea,
    const unsigned* __restrict__ rel, const int* __restrict__ rowoff,
    const int* __restrict__ modep, int e, int n, int B,
    int4* __restrict__ tmp, int* __restrict__ off2)
{
    __shared__ int  hcnt[SC_MAXB];
    __shared__ int  hoff[SC_MAXB + 1];
    __shared__ int4 stage[SC_CHUNK];
    int t = threadIdx.x;
    int c = blockIdx.x;
    int chunk0 = c * SC_CHUNK;
    int mode = modep[0], fm = modep[1];

    for (int q = t; q < B; q += 256) hcnt[q] = 0;
    __syncthreads();

    int  pos[8], sv[8], wv[8];
    bool val[8];
    #pragma unroll
    for (int k = 0; k < 8; k++){
        int i = chunk0 + k*256 + t;
        val[k] = false;
        if (i < e){
            int d = edge_dst(ei, e, i, mode);
            if ((unsigned)d < (unsigned)n){
                int s = edge_src(ei, e, i, mode);
                if ((unsigned)s >= (unsigned)n) s = 0;
                int p = rowoff[d] + (int)rel[i];
                pos[k] = p; sv[k] = s; wv[k] = __float_as_int(loadS(ea, i, fm));
                val[k] = true;
                atomicAdd(&hcnt[p >> SC_BSHIFT], 1);
            }
        }
    }
    __syncthreads();
    if (t == 0){
        int run = 0;
        for (int q = 0; q < B; q++){ hoff[q] = run; run += hcnt[q]; }
        hoff[B] = run;
    }
    __syncthreads();
    for (int q = t; q < B; q += 256) hcnt[q] = 0;
    for (int q = t; q <= B; q += 256) off2[(size_t)c*(B+1) + q] = hoff[q];
    __syncthreads();
    #pragma unroll
    for (int k = 0; k < 8; k++){
        if (val[k]){
            int b = pos[k] >> SC_BSHIFT;
            int slot = hoff[b] + atomicAdd(&hcnt[b], 1);
            stage[slot] = make_int4(pos[k], sv[k], wv[k], 0);
        }
    }
    __syncthreads();
    int tot = hoff[B];
    for (int idx = t; idx < tot; idx += 256)
        tmp[(size_t)chunk0 + idx] = stage[idx];
}

// ---- phase D: one block per bucket gathers all its pieces, writes colw ----
__global__ __launch_bounds__(512) void k_sfine(
    const int4* __restrict__ tmp, const int* __restrict__ off2,
    int B, int nchunks, int2* __restrict__ colw)
{
    int b = blockIdx.x;
    int wv = threadIdx.x >> 6, lane = threadIdx.x & 63;
    const int NW = 8;
    int c = wv;
    if (c >= nchunks) return;
    int s0 = off2[(size_t)c*(B+1) + b];
    int s1 = off2[(size_t)c*(B+1) + b + 1];
    while (true){
        int cn = c + NW;
        int n0 = 0, n1 = 0;
        if (cn < nchunks){
            n0 = off2[(size_t)cn*(B+1) + b];
            n1 = off2[(size_t)cn*(B+1) + b + 1];
        }
        int len = s1 - s0;
        size_t base = (size_t)c * SC_CHUNK + s0;
        for (int k = lane; k < len; k += 64){
            int4 ent = tmp[base + k];
            colw[ent.x] = make_int2(ent.y, ent.z);
        }
        if (cn >= nchunks) break;
        c = cn; s0 = n0; s1 = n1;
    }
}

// ---------------- weight prep ----------------
__global__ __launch_bounds__(64) void k_prep_w1(
    const void* __restrict__ W, const void* __restrict__ g, const void* __restrict__ b,
    const void* __restrict__ fc1b, const int* __restrict__ fmp,
    ushort_t* __restrict__ Wp, float* __restrict__ u, float* __restrict__ v)
{
    int fm = fmp[0];
    int j = blockIdx.x, lane = threadIdx.x;
    float su = 0.f, sv = 0.f;
    for (int k = lane; k < N_IN_F; k += 64){
        float w  = loadS(W, (size_t)j*N_IN_F + k, fm);
        float gk = loadS(g, k, fm);
        float bk = loadS(b, k, fm);
        unsigned short pw = f2bfu(gk * w);
        Wp[(size_t)j*N_IN_F + k] = pw;
        su += bfu2f(pw);
        sv += bk * w;
    }
    #pragma unroll
    for (int m = 32; m; m >>= 1){ su += __shfl_xor(su, m, 64); sv += __shfl_xor(sv, m, 64); }
    if (lane == 0){
        u[j] = su;
        v[j] = sv + loadS(fc1b, j, fm);
    }
}

__global__ void k_cvt4(const void* __restrict__ p0, const void* __restrict__ p1,
                       const void* __restrict__ p2, const void* __restrict__ p3,
                       const int* __restrict__ fmp, ushort_t* __restrict__ o)
{
    int fm = fmp[0];
    int i = blockIdx.x * 256 + threadIdx.x;
    if (i >= 49152) return;
    const void* p; int off;
    if (i < 16384)      { p = p0; off = i; }
    else if (i < 32768) { p = p1; off = i - 16384; }
    else if (i < 40960) { p = p2; off = i - 32768; }
    else                { p = p3; off = i - 40960; }
    o[i] = f2bfu(loadS(p, off, fm));
}

// ================= GEMM1 (fused LN1): direct-from-global MFMA fragments =================
// No LDS, no barriers. Lane (r16,kq) loads A[mw+r16][ks*32+kq*8..+8] (16B contig)
// and B[ni*16+r16][same k] (16B contig, Wp row-major [j][k]) straight into MFMA.
// Latency hidden by unrolled independent loads + VGPR-only occupancy.
__global__ __launch_bounds__(256) void k_gemm1_mfma(
    const void* __restrict__ x, const int* __restrict__ fmp,
    const ushort_t* __restrict__ Wp,
    const float* __restrict__ u, const float* __restrict__ v,
    ushort_t* __restrict__ out, int n)
{
    int fm = fmp[0];
    int t = threadIdx.x;
    int wave = t >> 6, lane = t & 63;
    int r16 = lane & 15, kq = lane >> 4;
    int m0 = blockIdx.x * 64;
    int mw = m0 + wave * 16;
    int grow = min(mw + r16, n - 1);

    const ushort_t* xbf = (const ushort_t*)x + (size_t)grow*N_IN_F + kq*8;
    const float*    xf  = (const float*)x    + (size_t)grow*N_IN_F + kq*8;
    const ushort_t* wpB = Wp + (size_t)r16*N_IN_F + kq*8;

    floatx4 acc[8];
    #pragma unroll
    for (int c = 0; c < 8; c++) acc[c] = (floatx4){0.f,0.f,0.f,0.f};
    float s1 = 0.f, s2 = 0.f;

    if (fm){
        #pragma unroll
        for (int ks = 0; ks < 12; ks++){
            short8v af = *(const short8v*)(xbf + ks*32);
            #pragma unroll
            for (int q = 0; q < 8; q++){
                float f = bfu2f((unsigned short)af[q]);
                s1 += f; s2 += f*f;
            }
            #pragma unroll
            for (int ni = 0; ni < 8; ni++){
                short8v bf = *(const short8v*)(wpB + (size_t)ni*16*N_IN_F + ks*32);
                acc[ni] = __builtin_amdgcn_mfma_f32_16x16x32_bf16(af, bf, acc[ni], 0, 0, 0);
            }
        }
    } else {
        #pragma unroll
        for (int ks = 0; ks < 12; ks++){
            floatx4 p = *(const floatx4*)(xf + ks*32);
            floatx4 q4 = *(const floatx4*)(xf + ks*32 + 4);
            union { ushort_t u[8]; short8v v; } w_;
            w_.u[0]=f2bfu(p[0]); w_.u[1]=f2bfu(p[1]); w_.u[2]=f2bfu(p[2]); w_.u[3]=f2bfu(p[3]);
            w_.u[4]=f2bfu(q4[0]); w_.u[5]=f2bfu(q4[1]); w_.u[6]=f2bfu(q4[2]); w_.u[7]=f2bfu(q4[3]);
            short8v af = w_.v;
            #pragma unroll
            for (int q = 0; q < 8; q++){
                float f = bfu2f((unsigned short)af[q]);
                s1 += f; s2 += f*f;
            }
            #pragma unroll
            for (int ni = 0; ni < 8; ni++){
                short8v bf = *(const short8v*)(wpB + (size_t)ni*16*N_IN_F + ks*32);
                acc[ni] = __builtin_amdgcn_mfma_f32_16x16x32_bf16(af, bf, acc[ni], 0, 0, 0);
            }
        }
    }

    // LN stats: reduce over the 4 kq-lanes of each row
    s1 += __shfl_xor(s1, 16, 64); s1 += __shfl_xor(s1, 32, 64);
    s2 += __shfl_xor(s2, 16, 64); s2 += __shfl_xor(s2, 32, 64);
    float mu = s1 * (1.f/384.f);
    float var = fmaxf(s2 * (1.f/384.f) - mu*mu, 0.f);
    float rs = rsqrtf(var + 1e-5f);

    float mm[4], rr[4];
    #pragma unroll
    for (int r = 0; r < 4; r++){
        mm[r] = __shfl(mu, kq*4 + r, 64);
        rr[r] = __shfl(rs, kq*4 + r, 64);
    }
    int ib = mw + kq*4;
    #pragma unroll
    for (int ni = 0; ni < 8; ni++){
        int j = ni*16 + r16;
        float uj = u[j], vj = v[j];
        #pragma unroll
        for (int r = 0; r < 4; r++){
            int ii = ib + r;
            float val = rr[r]*acc[ni][r] - rr[r]*mm[r]*uj + vj;
            if (ii < n) out[(size_t)ii*N_HID + j] = f2bfu(val);
        }
    }
}

// ================= conv1: leaky(A1@W1^T + A2@W2^T + b), direct-reg MFMA =================
__global__ __launch_bounds__(256) void k_conv1_mfma(
    const ushort_t* __restrict__ A1, const ushort_t* __restrict__ A2,
    const ushort_t* __restrict__ W1, const ushort_t* __restrict__ W2,
    const void* __restrict__ bias, const int* __restrict__ fmp,
    ushort_t* __restrict__ out, int n)
{
    int fm = fmp[0];
    int t = threadIdx.x;
    int wave = t >> 6, lane = t & 63;
    int r16 = lane & 15, kq = lane >> 4;
    int m0 = blockIdx.x * 64;
    int mw = m0 + wave * 16;
    int grow = min(mw + r16, n - 1);

    size_t aoff = (size_t)grow*N_HID + kq*8;
    size_t boff = (size_t)r16*N_HID + kq*8;

    floatx4 acc[8];
    #pragma unroll
    for (int c = 0; c < 8; c++) acc[c] = (floatx4){0.f,0.f,0.f,0.f};

    #pragma unroll
    for (int ks = 0; ks < 8; ks++){
        const ushort_t* Asrc = (ks < 4) ? A1 : A2;
        const ushort_t* Wsrc = (ks < 4) ? W1 : W2;
        int kb = (ks & 3) * 32;
        short8v af = *(const short8v*)(Asrc + aoff + kb);
        #pragma unroll
        for (int ni = 0; ni < 8; ni++){
            short8v bf = *(const short8v*)(Wsrc + boff + (size_t)ni*16*N_HID + kb);
            acc[ni] = __builtin_amdgcn_mfma_f32_16x16x32_bf16(af, bf, acc[ni], 0, 0, 0);
        }
    }

    int ib = mw + kq*4;
    #pragma unroll
    for (int ni = 0; ni < 8; ni++){
        int j = ni*16 + r16;
        float bb = loadS(bias, j, fm);
        #pragma unroll
        for (int r = 0; r < 4; r++){
            int ii = ib + r;
            float val = acc[ni][r] + bb;
            val = (val >= 0.f) ? val : 0.01f * val;
            if (ii < n) out[(size_t)ii*N_HID + j] = f2bfu(val);
        }
    }
}

// ================= conv2 + LN2 + fc2 fused, direct-reg MFMA =================
// tile 64 rows x 64 cols; 4 waves x (16 rows x 64 cols); K = 256.
__global__ __launch_bounds__(256) void k_conv2_final(
    const ushort_t* __restrict__ A1, const ushort_t* __restrict__ A2,
    const ushort_t* __restrict__ W1, const ushort_t* __restrict__ W2,
    const void* __restrict__ bias,
    const void* __restrict__ gam, const void* __restrict__ bet,
    const void* __restrict__ Wfc, const void* __restrict__ bfc,
    const int* __restrict__ fmp, void* __restrict__ out, int n)
{
    int fm = fmp[0];
    int t = threadIdx.x;
    int wave = t >> 6, lane = t & 63;
    int r16 = lane & 15, kq = lane >> 4;
    int m0 = blockIdx.x * 64;
    int mw = m0 + wave * 16;
    int grow = min(mw + r16, n - 1);

    size_t aoff = (size_t)grow*N_HID + kq*8;
    size_t boff = (size_t)r16*N_HID + kq*8;

    floatx4 acc[4];
    #pragma unroll
    for (int c = 0; c < 4; c++) acc[c] = (floatx4){0.f,0.f,0.f,0.f};

    #pragma unroll
    for (int ks = 0; ks < 8; ks++){
        const ushort_t* Asrc = (ks < 4) ? A1 : A2;
        const ushort_t* Wsrc = (ks < 4) ? W1 : W2;
        int kb = (ks & 3) * 32;
        short8v af = *(const short8v*)(Asrc + aoff + kb);
        #pragma unroll
        for (int ni = 0; ni < 4; ni++){
            short8v bf = *(const short8v*)(Wsrc + boff + (size_t)ni*16*N_HID + kb);
            acc[ni] = __builtin_amdgcn_mfma_f32_16x16x32_bf16(af, bf, acc[ni], 0, 0, 0);
        }
    }

    float b0 = loadS(bfc, 0, fm), b1 = loadS(bfc, 1, fm);
    // leaky + LN stats: row = mw + kq*4 + r; 64 cols over 16 lanes x 4 regs
    float s[4] = {}, s2[4] = {};
    #pragma unroll
    for (int ni = 0; ni < 4; ni++){
        int j = ni*16 + r16;
        float bb = loadS(bias, j, fm);
        #pragma unroll
        for (int r = 0; r < 4; r++){
            float val = acc[ni][r] + bb;
            val = (val >= 0.f) ? val : 0.01f * val;
            acc[ni][r] = val;
            s[r] += val; s2[r] += val*val;
        }
    }
    #pragma unroll
    for (int m = 1; m < 16; m <<= 1){
        #pragma unroll
        for (int r = 0; r < 4; r++){
            s[r]  += __shfl_xor(s[r],  m, 64);
            s2[r] += __shfl_xor(s2[r], m, 64);
        }
    }
    float mu[4], rstd[4];
    #pragma unroll
    for (int r = 0; r < 4; r++){
        mu[r] = s[r] * (1.f/64.f);
        float var = fmaxf(s2[r] * (1.f/64.f) - mu[r]*mu[r], 0.f);
        rstd[r] = rsqrtf(var + 1e-5f);
    }
    float p0[4] = {}, p1[4] = {};
    #pragma unroll
    for (int ni = 0; ni < 4; ni++){
        int j = ni*16 + r16;
        float gj = loadS(gam, j, fm), bj = loadS(bet, j, fm);
        float w0 = loadS(Wfc, j, fm), w1 = loadS(Wfc, 64 + j, fm);
        #pragma unroll
        for (int r = 0; r < 4; r++){
            float zn = (acc[ni][r] - mu[r]) * rstd[r] * gj + bj;
            p0[r] += zn * w0;
            p1[r] += zn * w1;
        }
    }
    #pragma unroll
    for (int m = 1; m < 16; m <<= 1){
        #pragma unroll
        for (int r = 0; r < 4; r++){
            p0[r] += __shfl_xor(p0[r], m, 64);
            p1[r] += __shfl_xor(p1[r], m, 64);
        }
    }
    if (r16 == 0){
        #pragma unroll
        for (int r = 0; r < 4; r++){
            int ii = mw + kq*4 + r;
            if (ii >= n) continue;
            float o0 = p0[r] + b0, o1 = p1[r] + b1;
            if (fm){
                unsigned pk = ((unsigned)f2bfu(o1) << 16) | (unsigned)f2bfu(o0);
                *(unsigned*)((ushort_t*)out + (size_t)ii*2) = pk;
            } else {
                float2 f2; f2.x = o0; f2.y = o1;
                *(float2*)((float*)out + (size_t)ii*2) = f2;
            }
        }
    }
}

// ---------------- CSR aggregation: 4-edge MLP, 16B row loads ----------------
__global__ __launch_bounds__(256) void k_agg(
    const int* __restrict__ rowoff, const int2* __restrict__ colw,
    const ushort_t* __restrict__ src_mat,   // [n,128] bf16
    ushort_t* __restrict__ out, int n, int eTot)
{
    int t = threadIdx.x;
    int lane = t & 63;
    int d = blockIdx.x * 4 + (t >> 6);
    if (d >= n) return;
    int grp = lane >> 4;
    int c16 = lane & 15;
    int e0 = rowoff[d], e1 = rowoff[d+1];
    e0 = max(0, min(e0, eTot));
    e1 = max(e0, min(e1, eTot));
    float acc[8] = {};
    for (int e = e0 + grp; e < e1; e += 4){
        int2 cw = colw[e];
        int s = cw.x;
        if ((unsigned)s >= (unsigned)n) s = 0;
        float wv = __int_as_float(cw.y);
        U8 u; u.v = *(const uint4*)(src_mat + (size_t)s*N_HID + c16*8);
        #pragma unroll
        for (int q = 0; q < 8; q++) acc[q] += wv * bfu2f(u.u[q]);
    }
    #pragma unroll
    for (int q = 0; q < 8; q++){
        acc[q] += __shfl_xor(acc[q], 16, 64);
        acc[q] += __shfl_xor(acc[q], 32, 64);
    }
    if (grp == 0){
        union { ushort_t u[8]; uint4 v; } P;
        #pragma unroll
        for (int q = 0; q < 8; q++) P.u[q] = f2bfu(acc[q]);
        *(uint4*)(out + (size_t)d*N_HID + c16*8) = P.v;
    }
}

// ---------------- launch ----------------
extern "C" void kernel_launch(void* const* d_in, const int* in_sizes, int n_in,
                              void* d_out, int out_size, void* d_ws, size_t ws_size,
                              hipStream_t stream)
{
    const void* x     = d_in[0];
    const int*  ei    = (const int*)d_in[1];
    const void* ea    = d_in[2];
    const void* ln1g  = d_in[3];
    const void* ln1b  = d_in[4];
    const void* fc1w  = d_in[5];
    const void* fc1b  = d_in[6];
    const void* c1rel = d_in[7];
    const void* c1bre = d_in[8];
    const void* c1roo = d_in[9];
    const void* c2rel = d_in[10];
    const void* c2bre = d_in[11];
    const void* c2roo = d_in[12];
    const void* ln2g  = d_in[13];
    const void* ln2b  = d_in[14];
    const void* fc2w  = d_in[15];
    const void* fc2b  = d_in[16];
    (void)n_in; (void)out_size; (void)ws_size;

    const int n = in_sizes[0] / N_IN_F;
    const int e = in_sizes[2];

    const int nchunks = (e + SC_CHUNK - 1) / SC_CHUNK;
    const int B = (e + (1 << SC_BSHIFT) - 1) >> SC_BSHIFT;

    char* wsp = (char*)d_ws;
    size_t off = 0;
    auto alloc = [&](size_t bytes) -> char* {
        char* p = wsp + off; off += (bytes + 255) & ~(size_t)255; return p;
    };
    int*      deg    = (int*)  alloc((size_t)n * 4);        // becomes cursor
    int*      rowoff = (int*)  alloc((size_t)(n+1) * 4);
    int*      part   = (int*)  alloc(4096);
    int*      modep  = (int*)  alloc(256);
    int2*     colw   = (int2*) alloc((size_t)e * 8);
    unsigned* rel    = (unsigned*)alloc((size_t)e * 4);
    int4*     stmp   = (int4*) alloc((size_t)e * 16);
    int*      off2   = (int*)  alloc((size_t)nchunks * (B+1) * 4);
    float*    u      = (float*)alloc(128 * 4);
    float*    v      = (float*)alloc(128 * 4);
    ushort_t* Wp     = (ushort_t*)alloc((size_t)N_HID * N_IN_F * 2);
    ushort_t* cw     = (ushort_t*)alloc((size_t)49152 * 2);
    ushort_t* h1     = (ushort_t*)alloc((size_t)n * N_HID * 2);
    ushort_t* agg1   = (ushort_t*)alloc((size_t)n * N_HID * 2);
    ushort_t* g1     = (ushort_t*)alloc((size_t)n * N_HID * 2);
    ushort_t* agg2   = h1;    // h1 dead after conv1 GEMM

    hipMemsetAsync(deg, 0, (size_t)n * 4, stream);
    k_detect_all<<<1, 64, 0, stream>>>(ei, (const unsigned*)x, modep);

    int nb = (n + 1023) / 1024;
    k_hist    <<<(e + 255) / 256, 256, 0, stream>>>(ei, e, n, modep, deg, rel);
    k_blksum  <<<nb, 1024, 0, stream>>>(deg, n, part);
    k_scanpart<<<1, 128, 0, stream>>>(part, nb, rowoff, n);
    k_scanblk <<<nb, 1024, 0, stream>>>(deg, part, n, rowoff);

    if (B <= SC_MAXB){
        k_scoarse<<<nchunks, 256, 0, stream>>>(ei, ea, rel, rowoff, modep, e, n, B, stmp, off2);
        k_sfine  <<<B, 512, 0, stream>>>(stmp, off2, B, nchunks, colw);
    } else {
        k_scatter<<<(e + 255) / 256, 256, 0, stream>>>(ei, ea, e, n, modep, deg, colw);
    }

    k_prep_w1<<<N_HID, 64, 0, stream>>>(fc1w, ln1g, ln1b, fc1b, modep + 1, Wp, u, v);
    k_cvt4   <<<(49152 + 255) / 256, 256, 0, stream>>>(c1rel, c1roo, c2rel, c2roo, modep + 1, cw);

    k_gemm1_mfma<<<(n + 63) / 64, 256, 0, stream>>>(x, modep + 1, Wp, u, v, h1, n);

    k_agg<<<(n + 3) / 4, 256, 0, stream>>>(rowoff, colw, h1, agg1, n, e);
    k_conv1_mfma<<<(n + 63) / 64, 256, 0, stream>>>(agg1, h1, cw, cw + 16384, c1bre, modep + 1, g1, n);

    k_agg<<<(n + 3) / 4, 256, 0, stream>>>(rowoff, colw, g1, agg2, n, e);
    k_conv2_final<<<(n + 63) / 64, 256, 0, stream>>>(agg2, g1, cw + 32768, cw + 40960, c2bre,
                                                     ln2g, ln2b, fc2w, fc2b, modep + 1, d_out, n);
}

// Round 8
// 628.331 us; speedup vs baseline: 1.1841x; 1.1841x over previous
//
#include <hip/hip_runtime.h>
#include <hip/hip_bf16.h>

#define N_IN_F 384
#define N_HID  128
#define N_OUT  64

typedef unsigned short ushort_t;
typedef __attribute__((ext_vector_type(8))) short short8v;   // 8 bf16 (4 VGPRs)
typedef __attribute__((ext_vector_type(4))) float floatx4;   // MFMA C/D

union U8 { uint4 v; unsigned short u[8]; };

__device__ __forceinline__ float bfu2f(unsigned short s){
    union { unsigned i; float f; } c; c.i = ((unsigned)s) << 16; return c.f;
}
__device__ __forceinline__ unsigned short f2bfu(float f){
    __hip_bfloat16 h = __float2bfloat16(f);
    union { __hip_bfloat16 h; unsigned short u; } c; c.h = h; return c.u;
}

// fm == 1: tensor is bf16; fm == 0: tensor is float32
__device__ __forceinline__ float loadS(const void* p, size_t i, int fm){
    return fm ? bfu2f(((const unsigned short*)p)[i]) : ((const float*)p)[i];
}

// ---------------- dtype probes ----------------
__global__ void k_detect_all(const int* __restrict__ ei, const unsigned* __restrict__ xw,
                             int* __restrict__ modep){
    int lane = threadIdx.x & 63;
    int zi = 0;
    if (lane < 32) zi = ei[2*lane + 1];
    int cnt = 0;
    #pragma unroll
    for (int q = 0; q < 8; q++){
        unsigned w = xw[lane*8 + q];
        unsigned elo = (w >> 7) & 0xff;
        cnt += (elo >= 118 && elo <= 134) ? 1 : 0;
    }
    #pragma unroll
    for (int m = 32; m; m >>= 1){ zi |= __shfl_xor(zi, m, 64); cnt += __shfl_xor(cnt, m, 64); }
    if (lane == 0 && blockIdx.x == 0){
        modep[0] = (zi == 0) ? 1 : 0;
        modep[1] = (cnt >= 256) ? 1 : 0;
    }
}

__device__ __forceinline__ int edge_src(const int* ei, int e, int i, int mode){
    return mode ? ei[2*(size_t)i] : ei[i];
}
__device__ __forceinline__ int edge_dst(const int* ei, int e, int i, int mode){
    return mode ? ei[2*(size_t)e + 2*(size_t)i] : ei[(size_t)e + i];
}

// ---------------- CSR build ----------------
__global__ void k_hist(const int* __restrict__ ei, int e, int n, const int* __restrict__ modep,
                       int* __restrict__ deg, unsigned* __restrict__ rel){
    int i = blockIdx.x * 256 + threadIdx.x;
    if (i >= e) return;
    int mode = modep[0];
    int d = edge_dst(ei, e, i, mode);
    if ((unsigned)d >= (unsigned)n) return;
    rel[i] = (unsigned)atomicAdd(&deg[d], 1);
}

__global__ __launch_bounds__(1024) void k_blksum(
    const int* __restrict__ deg, int n, int* __restrict__ part)
{
    __shared__ int s[1024];
    int i = blockIdx.x * 1024 + threadIdx.x;
    s[threadIdx.x] = (i < n) ? deg[i] : 0;
    __syncthreads();
    for (int off = 512; off; off >>= 1){
        if (threadIdx.x < off) s[threadIdx.x] += s[threadIdx.x + off];
        __syncthreads();
    }
    if (threadIdx.x == 0) part[blockIdx.x] = s[0];
}

__global__ __launch_bounds__(128) void k_scanpart(
    int* __restrict__ part, int nb, int* __restrict__ rowoff, int n)
{
    __shared__ int s[128];
    int t = threadIdx.x;
    if (nb <= 128){
        int v = (t < nb) ? part[t] : 0;
        s[t] = v; __syncthreads();
        #pragma unroll
        for (int off = 1; off < 128; off <<= 1){
            int tmp = (t >= off) ? s[t - off] : 0;
            __syncthreads();
            s[t] += tmp;
            __syncthreads();
        }
        if (t < nb) part[t] = s[t] - v;
        if (t == 127) rowoff[n] = s[127];
    } else if (t == 0){
        int run = 0;
        for (int b = 0; b < nb; b++){ int tt = part[b]; part[b] = run; run += tt; }
        rowoff[n] = run;
    }
}

__global__ __launch_bounds__(1024) void k_scanblk(
    int* __restrict__ deg, const int* __restrict__ part, int n, int* __restrict__ rowoff)
{
    __shared__ int s[1024];
    int t = threadIdx.x;
    int i = blockIdx.x * 1024 + t;
    int v = (i < n) ? deg[i] : 0;
    s[t] = v; __syncthreads();
    for (int off = 1; off < 1024; off <<= 1){
        int tmp = (t >= off) ? s[t - off] : 0;
        __syncthreads();
        s[t] += tmp;
        __syncthreads();
    }
    if (i < n){
        int excl = s[t] - v + part[blockIdx.x];
        rowoff[i] = excl;
        deg[i]    = excl;   // deg becomes the scatter cursor (fallback path)
    }
}

// ---- fallback scatter (random 8B writes) for degenerate shapes (B > 1024) ----
__global__ void k_scatter(const int* __restrict__ ei, const void* __restrict__ ea,
                          int e, int n, const int* __restrict__ modep,
                          int* __restrict__ cursor, int2* __restrict__ colw)
{
    int i = blockIdx.x * 256 + threadIdx.x;
    if (i >= e) return;
    int mode = modep[0], fm = modep[1];
    int d = edge_dst(ei, e, i, mode);
    if ((unsigned)d >= (unsigned)n) return;
    int s = edge_src(ei, e, i, mode);
    if ((unsigned)s >= (unsigned)n) s = 0;
    int pos = atomicAdd(&cursor[d], 1);
    if ((unsigned)pos >= (unsigned)e) return;
    int2 pk; pk.x = s; pk.y = __float_as_int(loadS(ea, i, fm));
    colw[pos] = pk;
}

// ---- phase C: block-local counting sort by pos-bucket, sequential dump ----
#define SC_CHUNK 2048
#define SC_BSHIFT 13
#define SC_MAXB 1024
__global__ __launch_bounds__(256) void k_scoarse(
    const int* __restrict__ ei, const void* __restrict__ ea,
    const unsigned* __restrict__ rel, const int* __restrict__ rowoff,
    const int* __restrict__ modep, int e, int n, int B,
    int4* __restrict__ tmp, int* __restrict__ off2)
{
    __shared__ int  hcnt[SC_MAXB];
    __shared__ int  hoff[SC_MAXB + 1];
    __shared__ int4 stage[SC_CHUNK];
    int t = threadIdx.x;
    int c = blockIdx.x;
    int chunk0 = c * SC_CHUNK;
    int mode = modep[0], fm = modep[1];

    for (int q = t; q < B; q += 256) hcnt[q] = 0;
    __syncthreads();

    int  pos[8], sv[8], wv[8];
    bool val[8];
    #pragma unroll
    for (int k = 0; k < 8; k++){
        int i = chunk0 + k*256 + t;
        val[k] = false;
        if (i < e){
            int d = edge_dst(ei, e, i, mode);
            if ((unsigned)d < (unsigned)n){
                int s = edge_src(ei, e, i, mode);
                if ((unsigned)s >= (unsigned)n) s = 0;
                int p = rowoff[d] + (int)rel[i];
                pos[k] = p; sv[k] = s; wv[k] = __float_as_int(loadS(ea, i, fm));
                val[k] = true;
                atomicAdd(&hcnt[p >> SC_BSHIFT], 1);
            }
        }
    }
    __syncthreads();
    if (t == 0){
        int run = 0;
        for (int q = 0; q < B; q++){ hoff[q] = run; run += hcnt[q]; }
        hoff[B] = run;
    }
    __syncthreads();
    for (int q = t; q < B; q += 256) hcnt[q] = 0;
    for (int q = t; q <= B; q += 256) off2[(size_t)c*(B+1) + q] = hoff[q];
    __syncthreads();
    #pragma unroll
    for (int k = 0; k < 8; k++){
        if (val[k]){
            int b = pos[k] >> SC_BSHIFT;
            int slot = hoff[b] + atomicAdd(&hcnt[b], 1);
            stage[slot] = make_int4(pos[k], sv[k], wv[k], 0);
        }
    }
    __syncthreads();
    int tot = hoff[B];
    for (int idx = t; idx < tot; idx += 256)
        tmp[(size_t)chunk0 + idx] = stage[idx];
}

// ---- phase D: one block per bucket gathers all its pieces, writes colw ----
__global__ __launch_bounds__(512) void k_sfine(
    const int4* __restrict__ tmp, const int* __restrict__ off2,
    int B, int nchunks, int2* __restrict__ colw)
{
    int b = blockIdx.x;
    int wv = threadIdx.x >> 6, lane = threadIdx.x & 63;
    const int NW = 8;
    int c = wv;
    if (c >= nchunks) return;
    int s0 = off2[(size_t)c*(B+1) + b];
    int s1 = off2[(size_t)c*(B+1) + b + 1];
    while (true){
        int cn = c + NW;
        int n0 = 0, n1 = 0;
        if (cn < nchunks){
            n0 = off2[(size_t)cn*(B+1) + b];
            n1 = off2[(size_t)cn*(B+1) + b + 1];
        }
        int len = s1 - s0;
        size_t base = (size_t)c * SC_CHUNK + s0;
        for (int k = lane; k < len; k += 64){
            int4 ent = tmp[base + k];
            colw[ent.x] = make_int2(ent.y, ent.z);
        }
        if (cn >= nchunks) break;
        c = cn; s0 = n0; s1 = n1;
    }
}

// ---------------- weight prep (FRAG-MAJOR output) ----------------
// Frag layout per 32-K chunk: idx = ((ks*NI + ni)*64 + kq*16 + r16)*8 + q
// where j = ni*16+r16 (out col), k = ks*32 + kq*8 + q. Lane-contiguous ds_reads.
__global__ __launch_bounds__(64) void k_prep_w1(
    const void* __restrict__ W, const void* __restrict__ g, const void* __restrict__ b,
    const void* __restrict__ fc1b, const int* __restrict__ fmp,
    ushort_t* __restrict__ Wp, float* __restrict__ u, float* __restrict__ v)
{
    int fm = fmp[0];
    int j = blockIdx.x, lane = threadIdx.x;
    int ni = j >> 4, r16 = j & 15;
    float su = 0.f, sv = 0.f;
    for (int k = lane; k < N_IN_F; k += 64){
        float w  = loadS(W, (size_t)j*N_IN_F + k, fm);
        float gk = loadS(g, k, fm);
        float bk = loadS(b, k, fm);
        unsigned short pw = f2bfu(gk * w);
        int idx = ((((k >> 5)*8 + ni)*64) + (((k >> 3) & 3) << 4) + r16)*8 + (k & 7);
        Wp[idx] = pw;
        su += bfu2f(pw);
        sv += bk * w;
    }
    #pragma unroll
    for (int m = 32; m; m >>= 1){ su += __shfl_xor(su, m, 64); sv += __shfl_xor(sv, m, 64); }
    if (lane == 0){
        u[j] = su;
        v[j] = sv + loadS(fc1b, j, fm);
    }
}

// conv weights -> frag-major bf16. Regions in o (ushorts):
// [0]=c1rel(16384) [16384]=c1roo(16384) [32768]=c2rel(8192) [40960]=c2roo(8192)
__global__ void k_cvt4(const void* __restrict__ p0, const void* __restrict__ p1,
                       const void* __restrict__ p2, const void* __restrict__ p3,
                       const int* __restrict__ fmp, ushort_t* __restrict__ o)
{
    int fm = fmp[0];
    int i = blockIdx.x * 256 + threadIdx.x;
    if (i >= 49152) return;
    const void* p; int off, base, NI;
    if (i < 16384)      { p = p0; off = i;         base = 0;     NI = 8; }
    else if (i < 32768) { p = p1; off = i - 16384; base = 16384; NI = 8; }
    else if (i < 40960) { p = p2; off = i - 32768; base = 32768; NI = 4; }
    else                { p = p3; off = i - 40960; base = 40960; NI = 4; }
    int j = off >> 7, k = off & 127;               // all mats have 128 cols (K)
    int fidx = ((((k >> 5)*NI + (j >> 4))*64) + (((k >> 3) & 3) << 4) + (j & 15))*8 + (k & 7);
    o[base + fidx] = f2bfu(loadS(p, off, fm));
}

// ================= GEMM1 (fused LN1): B-in-LDS-once, barrier-free K-loop =================
// 512 thr = 8 waves x 16 rows (128 rows/block). B staged frag-major in 2 halves
// (48KB LDS); K-loop: 1 contiguous global A-load + 8 conflict-free ds_read_b128
// + 8 MFMA per step, no barriers. 3 blocks/CU resident.
__global__ __launch_bounds__(512) void k_gemm1_mfma(
    const void* __restrict__ x, const int* __restrict__ fmp,
    const ushort_t* __restrict__ Wp,
    const float* __restrict__ u, const float* __restrict__ v,
    ushort_t* __restrict__ out, int n)
{
    __shared__ ushort_t Bs[24576];   // 6 chunks x 8 ni x 64 lanes x 8 = 48KB
    int fm = fmp[0];
    int t = threadIdx.x;
    int wave = t >> 6, lane = t & 63;
    int r16 = lane & 15, kq = lane >> 4;
    int m0 = blockIdx.x * 128;
    int mw = m0 + wave * 16;
    int grow = min(mw + r16, n - 1);

    const ushort_t* xbf = (const ushort_t*)x + (size_t)grow*N_IN_F + kq*8;
    const float*    xf  = (const float*)x    + (size_t)grow*N_IN_F + kq*8;

    floatx4 acc[8];
    #pragma unroll
    for (int c = 0; c < 8; c++) acc[c] = (floatx4){0.f,0.f,0.f,0.f};
    float s1 = 0.f, s2 = 0.f;

    #pragma unroll
    for (int h = 0; h < 2; h++){
        if (h) __syncthreads();
        {   // stage half of B (24576 ushorts = 6144 uint4), linear copy
            const uint4* src = (const uint4*)(Wp + h*24576);
            uint4* dst = (uint4*)Bs;
            #pragma unroll
            for (int q = 0; q < 12; q++) dst[t + q*512] = src[t + q*512];
        }
        __syncthreads();
        #pragma unroll
        for (int ksl = 0; ksl < 6; ksl++){
            int ks = h*6 + ksl;
            short8v af;
            if (fm){
                af = *(const short8v*)(xbf + ks*32);
            } else {
                floatx4 p  = *(const floatx4*)(xf + ks*32);
                floatx4 q4 = *(const floatx4*)(xf + ks*32 + 4);
                union { ushort_t u[8]; short8v v; } w_;
                w_.u[0]=f2bfu(p[0]);  w_.u[1]=f2bfu(p[1]);  w_.u[2]=f2bfu(p[2]);  w_.u[3]=f2bfu(p[3]);
                w_.u[4]=f2bfu(q4[0]); w_.u[5]=f2bfu(q4[1]); w_.u[6]=f2bfu(q4[2]); w_.u[7]=f2bfu(q4[3]);
                af = w_.v;
            }
            #pragma unroll
            for (int q = 0; q < 8; q++){
                float f = bfu2f((unsigned short)af[q]);
                s1 += f; s2 += f*f;
            }
            #pragma unroll
            for (int ni = 0; ni < 8; ni++){
                short8v bf = *(const short8v*)(Bs + ((ksl*8 + ni)*64 + lane)*8);
                acc[ni] = __builtin_amdgcn_mfma_f32_16x16x32_bf16(af, bf, acc[ni], 0, 0, 0);
            }
        }
    }

    // LN stats: reduce over the 4 kq-lanes of each row
    s1 += __shfl_xor(s1, 16, 64); s1 += __shfl_xor(s1, 32, 64);
    s2 += __shfl_xor(s2, 16, 64); s2 += __shfl_xor(s2, 32, 64);
    float mu = s1 * (1.f/384.f);
    float var = fmaxf(s2 * (1.f/384.f) - mu*mu, 0.f);
    float rs = rsqrtf(var + 1e-5f);

    float mm[4], rr[4];
    #pragma unroll
    for (int r = 0; r < 4; r++){
        mm[r] = __shfl(mu, kq*4 + r, 64);
        rr[r] = __shfl(rs, kq*4 + r, 64);
    }
    int ib = mw + kq*4;
    #pragma unroll
    for (int ni = 0; ni < 8; ni++){
        int j = ni*16 + r16;
        float uj = u[j], vj = v[j];
        #pragma unroll
        for (int r = 0; r < 4; r++){
            int ii = ib + r;
            float val = rr[r]*acc[ni][r] - rr[r]*mm[r]*uj + vj;
            if (ii < n) out[(size_t)ii*N_HID + j] = f2bfu(val);
        }
    }
}

// ================= conv1: leaky(A1@W1^T + A2@W2^T + b), B-in-LDS-once =================
__global__ __launch_bounds__(512) void k_conv1_mfma(
    const ushort_t* __restrict__ A1, const ushort_t* __restrict__ A2,
    const ushort_t* __restrict__ W1f, const ushort_t* __restrict__ W2f,
    const void* __restrict__ bias, const int* __restrict__ fmp,
    ushort_t* __restrict__ out, int n)
{
    __shared__ ushort_t Bs[16384];   // 4 chunks x 8 ni x 64 x 8 = 32KB
    int fm = fmp[0];
    int t = threadIdx.x;
    int wave = t >> 6, lane = t & 63;
    int r16 = lane & 15, kq = lane >> 4;
    int m0 = blockIdx.x * 128;
    int mw = m0 + wave * 16;
    int grow = min(mw + r16, n - 1);
    size_t aoff = (size_t)grow*N_HID + kq*8;

    floatx4 acc[8];
    #pragma unroll
    for (int c = 0; c < 8; c++) acc[c] = (floatx4){0.f,0.f,0.f,0.f};

    #pragma unroll
    for (int h = 0; h < 2; h++){
        if (h) __syncthreads();
        {
            const uint4* src = (const uint4*)(h ? W2f : W1f);
            uint4* dst = (uint4*)Bs;
            #pragma unroll
            for (int q = 0; q < 8; q++) dst[t + q*512] = src[t + q*512];
        }
        __syncthreads();
        const ushort_t* Asrc = h ? A2 : A1;
        #pragma unroll
        for (int ksl = 0; ksl < 4; ksl++){
            short8v af = *(const short8v*)(Asrc + aoff + ksl*32);
            #pragma unroll
            for (int ni = 0; ni < 8; ni++){
                short8v bf = *(const short8v*)(Bs + ((ksl*8 + ni)*64 + lane)*8);
                acc[ni] = __builtin_amdgcn_mfma_f32_16x16x32_bf16(af, bf, acc[ni], 0, 0, 0);
            }
        }
    }

    int ib = mw + kq*4;
    #pragma unroll
    for (int ni = 0; ni < 8; ni++){
        int j = ni*16 + r16;
        float bb = loadS(bias, j, fm);
        #pragma unroll
        for (int r = 0; r < 4; r++){
            int ii = ib + r;
            float val = acc[ni][r] + bb;
            val = (val >= 0.f) ? val : 0.01f * val;
            if (ii < n) out[(size_t)ii*N_HID + j] = f2bfu(val);
        }
    }
}

// ================= conv2 + LN2 + fc2 fused, B-in-LDS-once =================
// Wall = [c2rel frags 8192 | c2roo frags 8192] ushorts (32KB LDS, one stage).
__global__ __launch_bounds__(512) void k_conv2_final(
    const ushort_t* __restrict__ A1, const ushort_t* __restrict__ A2,
    const ushort_t* __restrict__ Wall,
    const void* __restrict__ bias,
    const void* __restrict__ gam, const void* __restrict__ bet,
    const void* __restrict__ Wfc, const void* __restrict__ bfc,
    const int* __restrict__ fmp, void* __restrict__ out, int n)
{
    __shared__ ushort_t Bs[16384];   // 32KB
    int fm = fmp[0];
    int t = threadIdx.x;
    int wave = t >> 6, lane = t & 63;
    int r16 = lane & 15, kq = lane >> 4;
    int m0 = blockIdx.x * 128;
    int mw = m0 + wave * 16;
    int grow = min(mw + r16, n - 1);
    size_t aoff = (size_t)grow*N_HID + kq*8;

    {
        const uint4* src = (const uint4*)Wall;
        uint4* dst = (uint4*)Bs;
        #pragma unroll
        for (int q = 0; q < 8; q++) dst[t + q*512] = src[t + q*512];
    }
    __syncthreads();

    floatx4 acc[4];
    #pragma unroll
    for (int c = 0; c < 4; c++) acc[c] = (floatx4){0.f,0.f,0.f,0.f};

    #pragma unroll
    for (int ks = 0; ks < 8; ks++){
        const ushort_t* Asrc = (ks < 4) ? A1 : A2;
        short8v af = *(const short8v*)(Asrc + aoff + (ks & 3)*32);
        int cbase = (ks < 4) ? 0 : 16;
        #pragma unroll
        for (int ni = 0; ni < 4; ni++){
            int chunk = cbase + (ks & 3)*4 + ni;
            short8v bf = *(const short8v*)(Bs + (chunk*64 + lane)*8);
            acc[ni] = __builtin_amdgcn_mfma_f32_16x16x32_bf16(af, bf, acc[ni], 0, 0, 0);
        }
    }

    float b0 = loadS(bfc, 0, fm), b1 = loadS(bfc, 1, fm);
    float s[4] = {}, s2[4] = {};
    #pragma unroll
    for (int ni = 0; ni < 4; ni++){
        int j = ni*16 + r16;
        float bb = loadS(bias, j, fm);
        #pragma unroll
        for (int r = 0; r < 4; r++){
            float val = acc[ni][r] + bb;
            val = (val >= 0.f) ? val : 0.01f * val;
            acc[ni][r] = val;
            s[r] += val; s2[r] += val*val;
        }
    }
    #pragma unroll
    for (int m = 1; m < 16; m <<= 1){
        #pragma unroll
        for (int r = 0; r < 4; r++){
            s[r]  += __shfl_xor(s[r],  m, 64);
            s2[r] += __shfl_xor(s2[r], m, 64);
        }
    }
    float mu[4], rstd[4];
    #pragma unroll
    for (int r = 0; r < 4; r++){
        mu[r] = s[r] * (1.f/64.f);
        float var = fmaxf(s2[r] * (1.f/64.f) - mu[r]*mu[r], 0.f);
        rstd[r] = rsqrtf(var + 1e-5f);
    }
    float p0[4] = {}, p1[4] = {};
    #pragma unroll
    for (int ni = 0; ni < 4; ni++){
        int j = ni*16 + r16;
        float gj = loadS(gam, j, fm), bj = loadS(bet, j, fm);
        float w0 = loadS(Wfc, j, fm), w1 = loadS(Wfc, 64 + j, fm);
        #pragma unroll
        for (int r = 0; r < 4; r++){
            float zn = (acc[ni][r] - mu[r]) * rstd[r] * gj + bj;
            p0[r] += zn * w0;
            p1[r] += zn * w1;
        }
    }
    #pragma unroll
    for (int m = 1; m < 16; m <<= 1){
        #pragma unroll
        for (int r = 0; r < 4; r++){
            p0[r] += __shfl_xor(p0[r], m, 64);
            p1[r] += __shfl_xor(p1[r], m, 64);
        }
    }
    if (r16 == 0){
        #pragma unroll
        for (int r = 0; r < 4; r++){
            int ii = mw + kq*4 + r;
            if (ii >= n) continue;
            float o0 = p0[r] + b0, o1 = p1[r] + b1;
            if (fm){
                unsigned pk = ((unsigned)f2bfu(o1) << 16) | (unsigned)f2bfu(o0);
                *(unsigned*)((ushort_t*)out + (size_t)ii*2) = pk;
            } else {
                float2 f2; f2.x = o0; f2.y = o1;
                *(float2*)((float*)out + (size_t)ii*2) = f2;
            }
        }
    }
}

// ---------------- CSR aggregation: 4-edge MLP, 16B row loads ----------------
__global__ __launch_bounds__(256) void k_agg(
    const int* __restrict__ rowoff, const int2* __restrict__ colw,
    const ushort_t* __restrict__ src_mat,   // [n,128] bf16
    ushort_t* __restrict__ out, int n, int eTot)
{
    int t = threadIdx.x;
    int lane = t & 63;
    int d = blockIdx.x * 4 + (t >> 6);
    if (d >= n) return;
    int grp = lane >> 4;
    int c16 = lane & 15;
    int e0 = rowoff[d], e1 = rowoff[d+1];
    e0 = max(0, min(e0, eTot));
    e1 = max(e0, min(e1, eTot));
    float acc[8] = {};
    for (int e = e0 + grp; e < e1; e += 4){
        int2 cw = colw[e];
        int s = cw.x;
        if ((unsigned)s >= (unsigned)n) s = 0;
        float wv = __int_as_float(cw.y);
        U8 u; u.v = *(const uint4*)(src_mat + (size_t)s*N_HID + c16*8);
        #pragma unroll
        for (int q = 0; q < 8; q++) acc[q] += wv * bfu2f(u.u[q]);
    }
    #pragma unroll
    for (int q = 0; q < 8; q++){
        acc[q] += __shfl_xor(acc[q], 16, 64);
        acc[q] += __shfl_xor(acc[q], 32, 64);
    }
    if (grp == 0){
        union { ushort_t u[8]; uint4 v; } P;
        #pragma unroll
        for (int q = 0; q < 8; q++) P.u[q] = f2bfu(acc[q]);
        *(uint4*)(out + (size_t)d*N_HID + c16*8) = P.v;
    }
}

// ---------------- launch ----------------
extern "C" void kernel_launch(void* const* d_in, const int* in_sizes, int n_in,
                              void* d_out, int out_size, void* d_ws, size_t ws_size,
                              hipStream_t stream)
{
    const void* x     = d_in[0];
    const int*  ei    = (const int*)d_in[1];
    const void* ea    = d_in[2];
    const void* ln1g  = d_in[3];
    const void* ln1b  = d_in[4];
    const void* fc1w  = d_in[5];
    const void* fc1b  = d_in[6];
    const void* c1rel = d_in[7];
    const void* c1bre = d_in[8];
    const void* c1roo = d_in[9];
    const void* c2rel = d_in[10];
    const void* c2bre = d_in[11];
    const void* c2roo = d_in[12];
    const void* ln2g  = d_in[13];
    const void* ln2b  = d_in[14];
    const void* fc2w  = d_in[15];
    const void* fc2b  = d_in[16];
    (void)n_in; (void)out_size; (void)ws_size;

    const int n = in_sizes[0] / N_IN_F;
    const int e = in_sizes[2];

    const int nchunks = (e + SC_CHUNK - 1) / SC_CHUNK;
    const int B = (e + (1 << SC_BSHIFT) - 1) >> SC_BSHIFT;

    char* wsp = (char*)d_ws;
    size_t off = 0;
    auto alloc = [&](size_t bytes) -> char* {
        char* p = wsp + off; off += (bytes + 255) & ~(size_t)255; return p;
    };
    int*      deg    = (int*)  alloc((size_t)n * 4);        // becomes cursor
    int*      rowoff = (int*)  alloc((size_t)(n+1) * 4);
    int*      part   = (int*)  alloc(4096);
    int*      modep  = (int*)  alloc(256);
    int2*     colw   = (int2*) alloc((size_t)e * 8);
    unsigned* rel    = (unsigned*)alloc((size_t)e * 4);
    int4*     stmp   = (int4*) alloc((size_t)e * 16);
    int*      off2   = (int*)  alloc((size_t)nchunks * (B+1) * 4);
    float*    u      = (float*)alloc(128 * 4);
    float*    v      = (float*)alloc(128 * 4);
    ushort_t* Wp     = (ushort_t*)alloc((size_t)N_HID * N_IN_F * 2);
    ushort_t* cw     = (ushort_t*)alloc((size_t)49152 * 2);
    ushort_t* h1     = (ushort_t*)alloc((size_t)n * N_HID * 2);
    ushort_t* agg1   = (ushort_t*)alloc((size_t)n * N_HID * 2);
    ushort_t* g1     = (ushort_t*)alloc((size_t)n * N_HID * 2);
    ushort_t* agg2   = h1;    // h1 dead after conv1 GEMM

    hipMemsetAsync(deg, 0, (size_t)n * 4, stream);
    k_detect_all<<<1, 64, 0, stream>>>(ei, (const unsigned*)x, modep);

    int nb = (n + 1023) / 1024;
    k_hist    <<<(e + 255) / 256, 256, 0, stream>>>(ei, e, n, modep, deg, rel);
    k_blksum  <<<nb, 1024, 0, stream>>>(deg, n, part);
    k_scanpart<<<1, 128, 0, stream>>>(part, nb, rowoff, n);
    k_scanblk <<<nb, 1024, 0, stream>>>(deg, part, n, rowoff);

    if (B <= SC_MAXB){
        k_scoarse<<<nchunks, 256, 0, stream>>>(ei, ea, rel, rowoff, modep, e, n, B, stmp, off2);
        k_sfine  <<<B, 512, 0, stream>>>(stmp, off2, B, nchunks, colw);
    } else {
        k_scatter<<<(e + 255) / 256, 256, 0, stream>>>(ei, ea, e, n, modep, deg, colw);
    }

    k_prep_w1<<<N_HID, 64, 0, stream>>>(fc1w, ln1g, ln1b, fc1b, modep + 1, Wp, u, v);
    k_cvt4   <<<(49152 + 255) / 256, 256, 0, stream>>>(c1rel, c1roo, c2rel, c2roo, modep + 1, cw);

    k_gemm1_mfma<<<(n + 127) / 128, 512, 0, stream>>>(x, modep + 1, Wp, u, v, h1, n);

    k_agg<<<(n + 3) / 4, 256, 0, stream>>>(rowoff, colw, h1, agg1, n, e);
    k_conv1_mfma<<<(n + 127) / 128, 512, 0, stream>>>(agg1, h1, cw, cw + 16384, c1bre, modep + 1, g1, n);

    k_agg<<<(n + 3) / 4, 256, 0, stream>>>(rowoff, colw, g1, agg2, n, e);
    k_conv2_final<<<(n + 127) / 128, 512, 0, stream>>>(agg2, g1, cw + 32768, c2bre,
                                                       ln2g, ln2b, fc2w, fc2b, modep + 1, d_out, n);
}